// Round 4
// baseline (356.632 us; speedup 1.0000x reference)
//
#include <hip/hip_runtime.h>

typedef __bf16 bf16x8 __attribute__((ext_vector_type(8)));
typedef __bf16 bf16x4 __attribute__((ext_vector_type(4)));
typedef float  floatx4 __attribute__((ext_vector_type(4)));

#define GLOBAL_AS __attribute__((address_space(1)))
#define LOCAL_AS  __attribute__((address_space(3)))

static constexpr int HID = 1024;
static constexpr int MT  = 128;   // samples per block
static constexpr int KB  = 256;   // k-block resident in LDS
static constexpr int NKB = HID / KB;  // 4

// ---------------------------------------------------------------------------
// Prep 1: W2 [K][N] fp32 -> W2F in MFMA-A-fragment order: one wave fragment
// (16 cols x 32 k) is 1024 contiguous bytes; lane l holds col = l&15,
// k-octet = l>>4. In-kernel B-reads become perfectly coalesced dwordx4.
// W2F[((n16*32 + k32)*64 + lane)*8 + j] = W2[k32*32 + (lane>>4)*8 + j][n16*16 + (lane&15)]
// ---------------------------------------------------------------------------
__global__ __launch_bounds__(256)
void prep_w2f(const float* __restrict__ W2, __bf16* __restrict__ W2F) {
    const int g    = blockIdx.x * 256 + threadIdx.x;   // [0, 131072)
    const int lane = g & 63;
    const int k32  = (g >> 6) & 31;
    const int n16  = g >> 11;
    const int col  = n16 * 16 + (lane & 15);
    const int kb   = k32 * 32 + (lane >> 4) * 8;
    bf16x8 v;
#pragma unroll
    for (int j = 0; j < 8; ++j) v[j] = (__bf16)W2[(size_t)(kb + j) * HID + col];
    *(bf16x8*)(W2F + (size_t)g * 8) = v;
}

// ---------------------------------------------------------------------------
// Prep 2: W_heads [5][H][4] fp32 -> WHT [32][H] bf16 (row = skill*4+action,
// rows 20..31 zero), octet-XOR swizzle per 128-col chunk (r2-verified).
// ---------------------------------------------------------------------------
__global__ __launch_bounds__(256)
void prep_wh(const float* __restrict__ WH, __bf16* __restrict__ WHT) {
    const int r = blockIdx.x;          // 0..31
    const int s = r >> 2, a = r & 3;
    for (int k = threadIdx.x; k < HID; k += 256) {
        const float v = (r < 20) ? WH[((size_t)s * HID + k) * 4 + a] : 0.f;
        const int c = k >> 7, o = (k >> 3) & 15, j = k & 7;
        const int sw = (o & 8) | ((o & 7) ^ (r & 7));
        WHT[(size_t)r * HID + c * 128 + sw * 8 + j] = (__bf16)v;
    }
}

__device__ __forceinline__ void h8(bf16x8& d, float s0, float s1,
                                   const float4& w0a, const float4& w0b,
                                   const float4& w1a, const float4& w1b,
                                   const float4& ba,  const float4& bb) {
    d[0] = (__bf16)fmaxf(fmaf(s1, w1a.x, fmaf(s0, w0a.x, ba.x)), 0.f);
    d[1] = (__bf16)fmaxf(fmaf(s1, w1a.y, fmaf(s0, w0a.y, ba.y)), 0.f);
    d[2] = (__bf16)fmaxf(fmaf(s1, w1a.z, fmaf(s0, w0a.z, ba.z)), 0.f);
    d[3] = (__bf16)fmaxf(fmaf(s1, w1a.w, fmaf(s0, w0a.w, ba.w)), 0.f);
    d[4] = (__bf16)fmaxf(fmaf(s1, w1b.x, fmaf(s0, w0b.x, bb.x)), 0.f);
    d[5] = (__bf16)fmaxf(fmaf(s1, w1b.y, fmaf(s0, w0b.y, bb.y)), 0.f);
    d[6] = (__bf16)fmaxf(fmaf(s1, w1b.z, fmaf(s0, w0b.z, bb.z)), 0.f);
    d[7] = (__bf16)fmaxf(fmaf(s1, w1b.w, fmaf(s0, w0b.w, bb.w)), 0.f);
}

// ---------------------------------------------------------------------------
// Fused kernel, barrier-light: W2 streams global->VGPR (fragment-ordered,
// coalesced, NO LDS staging, no vmcnt(0) drains in the K-stream). LDS holds
// only the shared h k-block (single buffer, 64 KB). Block = 128 samples x
// 512 featcols (half); halves combine via atomicAdd on pre-zeroed OUT.
// 512 threads = 8 waves; wave w owns featcols w*64..+63 (main) and samples
// w*16..+15 (head).
// LDS (65536 B): hL [128][256] bf16 swizzled.
// Epilogue overlays: featL @0 [128][136] bf16 (34816) | WHTL @34816 [32][128]
// bf16 (8192) | headL @43008 [32][132] f32 (16896) -> 59904 <= 65536.
// ---------------------------------------------------------------------------
__global__ __launch_bounds__(512, 2)
void policy_fused(const float* __restrict__ S,  const int* __restrict__ SK,
                  const float* __restrict__ W1, const float* __restrict__ B1,
                  const __bf16* __restrict__ W2F, const float* __restrict__ B2,
                  const __bf16* __restrict__ WHT, const float* __restrict__ BH,
                  float* __restrict__ OUT) {
    __shared__ __align__(16) char smem[65536];
    __bf16* hL    = (__bf16*)smem;            // [128][256] swizzled
    __bf16* featL = (__bf16*)smem;            // overlay [128][136]
    __bf16* WHTL  = (__bf16*)(smem + 34816);  // overlay [32][128]
    float*  headL = (float*)(smem + 43008);   // overlay [32][132]

    const int tid  = threadIdx.x;
    const int lane = tid & 63;
    const int wv   = tid >> 6;   // 0..7
    const int l15  = lane & 15;
    const int quad = lane >> 4;
    const int mg   = blockIdx.x >> 1;
    const int half = blockIdx.x & 1;
    const int i0   = mg * MT;

    // h-gen: thread -> sample (tid>>2), octet group (tid&3)*8..+7 of 32 octets
    const int hs = tid >> 2;     // 0..127
    const int hq = tid & 3;
    const float s0 = S[(i0 + hs) * 2 + 0];
    const float s1 = S[(i0 + hs) * 2 + 1];

    floatx4 acc[4][8] = {};   // [fn featcol-frag][fm sample-frag]
    floatx4 hacc[2] = {};     // head acc: headcol tiles 0,1

#pragma unroll 1
    for (int kb = 0; kb < NKB; ++kb) {
        // ---- gen h[128][256] for this k-block into LDS (swizzled octets)
#pragma unroll
        for (int i = 0; i < 8; ++i) {
            const int o  = hq * 8 + i;           // octet 0..31
            const int kg = kb * KB + o * 8;
            const float4 w0a = *(const float4*)(W1 + kg);
            const float4 w0b = *(const float4*)(W1 + kg + 4);
            const float4 w1a = *(const float4*)(W1 + HID + kg);
            const float4 w1b = *(const float4*)(W1 + HID + kg + 4);
            const float4 bba = *(const float4*)(B1 + kg);
            const float4 bbb = *(const float4*)(B1 + kg + 4);
            bf16x8 hv;
            h8(hv, s0, s1, w0a, w0b, w1a, w1b, bba, bbb);
            const int sw = (o & 24) | ((o & 7) ^ (hs & 7));
            *(bf16x8*)(hL + hs * 256 + sw * 8) = hv;
        }
        __syncthreads();   // h visible (LDS-only wait)

        // ---- K-stream: 8 k-steps of 32; B from global (coalesced frags)
#pragma unroll
        for (int ks = 0; ks < 8; ++ks) {
            const int k32 = kb * 8 + ks;
            bf16x8 wf[4], hf[8];
#pragma unroll
            for (int fn = 0; fn < 4; ++fn) {
                const int n16 = half * 32 + wv * 4 + fn;
                wf[fn] = *(const bf16x8*)(W2F + ((size_t)(n16 * 32 + k32) * 64 + lane) * 8);
            }
#pragma unroll
            for (int fm = 0; fm < 8; ++fm) {
                const int smp = fm * 16 + l15;
                const int o   = ks * 4 + quad;
                const int sw  = (o & 24) | ((o & 7) ^ (smp & 7));
                hf[fm] = *(const bf16x8*)(hL + smp * 256 + sw * 8);
            }
#pragma unroll
            for (int fn = 0; fn < 4; ++fn)
#pragma unroll
                for (int fm = 0; fm < 8; ++fm)
                    acc[fn][fm] = __builtin_amdgcn_mfma_f32_16x16x32_bf16(
                        wf[fn], hf[fm], acc[fn][fm], 0, 0, 0);
        }
        __syncthreads();   // readers done before hL rewrite / epilogue overlay
    }

    // ---- epilogue: 4 chunks of 128 cols; featL + head MFMA (r2-verified)
#pragma unroll
    for (int chunk = 0; chunk < 4; ++chunk) {
        if ((wv >> 1) == chunk) {   // waves 2c,2c+1 own these cols
#pragma unroll
            for (int fn = 0; fn < 4; ++fn) {
                const int fcb = (wv & 1) * 64 + fn * 16 + quad * 4;  // 0..124
                const float4 b2v = *(const float4*)(B2 + half * 512 + chunk * 128 + fcb);
#pragma unroll
                for (int fm = 0; fm < 8; ++fm) {
                    const floatx4 v = acc[fn][fm];
                    bf16x4 p;
                    p[0] = (__bf16)fmaxf(v[0] + b2v.x, 0.f);
                    p[1] = (__bf16)fmaxf(v[1] + b2v.y, 0.f);
                    p[2] = (__bf16)fmaxf(v[2] + b2v.z, 0.f);
                    p[3] = (__bf16)fmaxf(v[3] + b2v.w, 0.f);
                    *(bf16x4*)(featL + (fm * 16 + l15) * 136 + fcb) = p;
                }
            }
        }
        // stage WHT chunk [32][128] (1 global_load_lds per wave)
        {
            const int rb = wv * 4;
            const __bf16* gp = WHT + (size_t)(rb + (lane >> 4)) * HID
                             + half * 512 + chunk * 128 + (lane & 15) * 8;
            __builtin_amdgcn_global_load_lds((GLOBAL_AS void*)gp,
                                             (LOCAL_AS void*)(WHTL + rb * 128), 16, 0, 0);
        }
        __syncthreads();
        // head MFMA: wave w -> samples w*16..+15, both headcol tiles, K=128
#pragma unroll
        for (int ks2 = 0; ks2 < 4; ++ks2) {
            const bf16x8 fa = *(const bf16x8*)(featL + (wv * 16 + l15) * 136
                                               + ks2 * 32 + quad * 8);
#pragma unroll
            for (int nt2 = 0; nt2 < 2; ++nt2) {
                const int r = nt2 * 16 + l15;
                const int o = ks2 * 4 + quad;
                const int sw = (o & 8) | ((o & 7) ^ (r & 7));
                const bf16x8 wb = *(const bf16x8*)(WHTL + r * 128 + sw * 8);
                hacc[nt2] = __builtin_amdgcn_mfma_f32_16x16x32_bf16(
                    fa, wb, hacc[nt2], 0, 0, 0);
            }
        }
        __syncthreads();   // featL/WHTL reusable for next chunk
    }

    // ---- select per sample and atomically combine the two halves
#pragma unroll
    for (int nt2 = 0; nt2 < 2; ++nt2)
        *(floatx4*)(headL + (nt2 * 16 + l15) * 132 + wv * 16 + quad * 4) = hacc[nt2];
    __syncthreads();
    {
        const int smp = tid >> 2, a = tid & 3;
        const int sk  = SK[i0 + smp];
        float v = headL[(sk * 4 + a) * 132 + smp];
        if (half == 0) v += BH[sk * 4 + a];
        atomicAdd(&OUT[(size_t)(i0 + smp) * 4 + a], v);
    }
}

extern "C" void kernel_launch(void* const* d_in, const int* in_sizes, int n_in,
                              void* d_out, int out_size, void* d_ws, size_t ws_size,
                              hipStream_t stream) {
    const float* S  = (const float*)d_in[0];
    const int*   SK = (const int*)d_in[1];
    const float* W1 = (const float*)d_in[2];
    const float* B1 = (const float*)d_in[3];
    const float* W2 = (const float*)d_in[4];
    const float* B2 = (const float*)d_in[5];
    const float* WH = (const float*)d_in[6];
    const float* BH = (const float*)d_in[7];
    __bf16* W2F = (__bf16*)d_ws;                            // 2 MiB frag-ordered
    __bf16* WHT = (__bf16*)((char*)d_ws + 2 * 1024 * 1024); // 64 KiB

    hipMemsetAsync(d_out, 0, (size_t)out_size * sizeof(float), stream);
    hipLaunchKernelGGL(prep_w2f, dim3(512), dim3(256), 0, stream, W2, W2F);
    hipLaunchKernelGGL(prep_wh, dim3(32), dim3(256), 0, stream, WH, WHT);
    hipLaunchKernelGGL(policy_fused, dim3((65536 / MT) * 2), dim3(512), 0, stream,
                       S, SK, W1, B1, W2F, B2, WHT, BH, (float*)d_out);
}